// Round 8
// baseline (740.992 us; speedup 1.0000x reference)
//
#include <hip/hip_runtime.h>
#include <hip/hip_bf16.h>
#include <stdint.h>

#define TT 4096   // tokens = B*S
#define HH 1024   // hidden
#define II 2048   // intermediate
#define EE 8      // experts
#define RB 16     // router tokens per block
#define NRB (TT / RB)          // 256 router blocks
#define CSTRIDE 32             // cnt padding: one counter per 128-B line
#define NTRB (2 * 2048)        // gate/up transpose blocks in front
#define NZB 256                // zero blocks

typedef short bf16x8 __attribute__((ext_vector_type(8)));
typedef float f32x4 __attribute__((ext_vector_type(4)));

__device__ __forceinline__ unsigned short f2bf(float f) {
  unsigned u = __float_as_uint(f);
  u += 0x7FFF + ((u >> 16) & 1);   // RNE
  return (unsigned short)(u >> 16);
}

__device__ __forceinline__ void gl_lds16(const void* g, void* l) {
  auto gp = reinterpret_cast<const __attribute__((address_space(1))) unsigned int*>(
      reinterpret_cast<uintptr_t>(g));
  auto lp = reinterpret_cast<__attribute__((address_space(3))) unsigned int*>(
      reinterpret_cast<uintptr_t>(l));
  __builtin_amdgcn_global_load_lds(gp, lp, 16, 0, 0);
}

// ------- 64(M) x 128(N) transpose tile: in[M][N] fp32 -> out[N][M] bf16 -------
__device__ __forceinline__ void transpose_tile_wide(const float* __restrict__ in,
                                                    unsigned short* __restrict__ out,
                                                    int M, int N, int mB, int nB,
                                                    unsigned int* tl, int tid) {
  union F4 { float4 v; float f[4]; };
  int n4 = tid & 31;          // col quad 0..31
  int mph = tid >> 5;         // 0..7
  F4 a[4], bq[4];
  const float* base = in + (size_t)mB * N + nB + n4 * 4;
#pragma unroll
  for (int it = 0; it < 4; ++it) {
    const float* p = base + (size_t)(2 * (mph + it * 8)) * N;
    a[it].v = *(const float4*)p;
    bq[it].v = *(const float4*)(p + N);
  }
#pragma unroll
  for (int it = 0; it < 4; ++it) {
    int mp = mph + it * 8;    // 0..31
#pragma unroll
    for (int i = 0; i < 4; ++i) {
      int n = n4 * 4 + i;
      unsigned v = (unsigned)f2bf(a[it].f[i]) | ((unsigned)f2bf(bq[it].f[i]) << 16);
      tl[n * 32 + ((mp + (n >> 2) + (n & 3)) & 31)] = v;
    }
  }
  __syncthreads();
  int md = tid & 7;           // dword group (x4)
  int nr = tid >> 3;          // 0..31
#pragma unroll
  for (int it = 0; it < 4; ++it) {
    int n = nr + it * 32;     // 0..127
    int rot = (n >> 2) + (n & 3);
    unsigned vv[4];
#pragma unroll
    for (int k = 0; k < 4; ++k)
      vv[k] = tl[n * 32 + ((md * 4 + k + rot) & 31)];
    *(uint4*)(out + (size_t)(nB + n) * M + mB + md * 8) = make_uint4(vv[0], vv[1], vv[2], vv[3]);
  }
}

// ------- front: router + gate/up transposes + out-buffer zeroing -------
__global__ __launch_bounds__(256, 4)
void front_kernel(const float* __restrict__ x, const float* __restrict__ rw,
                  const float* __restrict__ gw, const float* __restrict__ uw,
                  float* __restrict__ logits_out, unsigned short* __restrict__ xb,
                  unsigned short* __restrict__ gwt, unsigned short* __restrict__ uwt,
                  int* __restrict__ gcnt, int2* __restrict__ ttop,
                  float* __restrict__ outz) {
  __shared__ unsigned int tl[4096];   // 16 KB
  int b = blockIdx.x;
  int tid = threadIdx.x;

  if (b >= NRB + NTRB) {
    // zero out[0..TT*HH): 256 blocks x 256 thr x 16 float4
    int zb = b - NRB - NTRB;              // 0..255
    float4* o = (float4*)outz + (size_t)zb * 4096 + tid;
    float4 z = make_float4(0.f, 0.f, 0.f, 0.f);
#pragma unroll
    for (int k = 0; k < 16; ++k) o[k * 256] = z;
    return;
  }

  if (b >= NRB) {
    int idx = b - NRB;           // 0..4095
    int which = idx >> 11;       // 0 gate, 1 up
    int r = idx & 2047;
    int e = r >> 8;              // 256 tiles per expert per matrix
    int tile = r & 255;
    // in [HH][II]: M=1024 -> 16 m-tiles of 64, N=2048 -> 16 n-tiles of 128
    int bx = tile & 15, by = tile >> 4;
    const float* in = (which ? uw : gw) + (size_t)e * HH * II;
    unsigned short* o = (which ? uwt : gwt) + (size_t)e * HH * II;
    transpose_tile_wide(in, o, HH, II, by * 64, bx * 128, tl, tid);
    return;
  }

  __shared__ int bcnt[EE];
  int wave = tid >> 6, lane = tid & 63;
  if (tid < EE) bcnt[tid] = 0;
  __syncthreads();
  int t0 = b * RB;

  for (int sub = 0; sub < RB / 4; ++sub) {
    int li = sub * 4 + wave;
    int t = t0 + li;
    float acc[EE];
#pragma unroll
    for (int e = 0; e < EE; ++e) acc[e] = 0.f;
#pragma unroll
    for (int j = 0; j < 4; ++j) {
      int h = j * 256 + lane * 4;
      union F4 { float4 v; float f[4]; } xv;
      xv.v = *(const float4*)(x + (size_t)t * HH + h);
      union { unsigned short s[4]; uint2 v; } pk;
#pragma unroll
      for (int i = 0; i < 4; ++i) pk.s[i] = f2bf(xv.f[i]);
      *(uint2*)(xb + (size_t)t * HH + h) = pk.v;
#pragma unroll
      for (int i = 0; i < 4; ++i) {
        const float4* r4 = (const float4*)(rw + (h + i) * EE);
        float4 r0 = r4[0], r1 = r4[1];
        float xs = xv.f[i];
        acc[0] += xs * r0.x; acc[1] += xs * r0.y; acc[2] += xs * r0.z; acc[3] += xs * r0.w;
        acc[4] += xs * r1.x; acc[5] += xs * r1.y; acc[6] += xs * r1.z; acc[7] += xs * r1.w;
      }
    }
#pragma unroll
    for (int e = 0; e < EE; ++e)
#pragma unroll
      for (int off = 32; off; off >>= 1) acc[e] += __shfl_down(acc[e], off);
    if (lane == 0) {
      float4* lo = (float4*)(logits_out + (size_t)t * EE);
      lo[0] = make_float4(acc[0], acc[1], acc[2], acc[3]);
      lo[1] = make_float4(acc[4], acc[5], acc[6], acc[7]);
      int e0 = 0; float b0 = acc[0];
#pragma unroll
      for (int e = 1; e < EE; ++e) if (acc[e] > b0) { b0 = acc[e]; e0 = e; }
      int e1 = -1; float b1 = -3.4e38f;
#pragma unroll
      for (int e = 0; e < EE; ++e) if (e != e0 && acc[e] > b1) { b1 = acc[e]; e1 = e; }
      float w0 = 1.f / (1.f + __expf(b1 - b0));
      int lp0 = atomicAdd(&bcnt[e0], 1);   // LDS atomic, intra-block only
      int lp1 = atomicAdd(&bcnt[e1], 1);
      ttop[t] = make_int2(e0 | (e1 << 3) | (lp0 << 6) | (lp1 << 11), __float_as_int(w0));
    }
  }
  __syncthreads();
  if (tid < EE) gcnt[b * EE + tid] = bcnt[tid];
}

// ------- scatter: deterministic token placement; emits per-(e,slot) token + weight -------
__global__ void scatter_kernel(const int* __restrict__ gcnt, const int2* __restrict__ ttop,
                               int* __restrict__ cnt, int* __restrict__ list,
                               float* __restrict__ rwt) {
  __shared__ int raw[NRB * EE];
  __shared__ int base[NRB][EE];
  int tid = threadIdx.x;
  for (int i = tid; i < NRB * EE; i += 256) raw[i] = gcnt[i];
  __syncthreads();
  if (tid < EE) {
    int s = 0;
    for (int b = 0; b < NRB; ++b) { base[b][tid] = s; s += raw[b * EE + tid]; }
    if (blockIdx.x == 0) cnt[tid * CSTRIDE] = s;
  }
  __syncthreads();
  int t = blockIdx.x * 256 + tid;
  int2 ti = ttop[t];
  int v = ti.x;
  float w0 = __int_as_float(ti.y);
  int e0 = v & 7, e1 = (v >> 3) & 7, lp0 = (v >> 6) & 31, lp1 = (v >> 11) & 31;
  int b = t >> 4;
  int p0 = base[b][e0] + lp0;
  int p1 = base[b][e1] + lp1;
  list[e0 * TT + p0] = t;
  list[e1 * TT + p1] = t;
  rwt[e0 * TT + p0] = w0;
  rwt[e1 * TT + p1] = 1.f - w0;
}

// ---------------- GEMM1: grouped GEMM, 128(M) x 64(N) x2 tensors, BK=32 dbuf ----------------
// blockIdx.x = m-tile (fastest -> consecutive blocks share B panel, XCD-L2 resident).
// blockIdx.y in [32,40): embedded out_w transpose tiles (backfill; round-0/7 proven).
__launch_bounds__(256, 4)
__global__ void gemm1_kernel(const unsigned short* __restrict__ xb,
                             const unsigned short* __restrict__ gwt,
                             const unsigned short* __restrict__ uwt,
                             const float* __restrict__ ow, unsigned short* __restrict__ owt,
                             unsigned short* __restrict__ hidden,
                             const int* __restrict__ cnt, const int* __restrict__ list) {
  __shared__ __align__(16) unsigned short smem[16384];  // 2 buffers x 1024 x 16B chunks
  __shared__ int stok[128];
  int tid = threadIdx.x;
  int e = blockIdx.z;

  if (blockIdx.y >= 32) {
    // out_w transpose: ow [II][HH] -> owt [HH][II] for expert e
    int tile = (blockIdx.y - 32) * 32 + blockIdx.x;  // 0..255
    int bx = tile & 7, by = tile >> 3;               // N/128=8, M/64=32
    transpose_tile_wide(ow + (size_t)e * II * HH, owt + (size_t)e * II * HH,
                        II, HH, by * 64, bx * 128, (unsigned int*)smem, tid);
    return;
  }

  int cn = cnt[e * CSTRIDE];
  int hb0 = 0;
  for (int i = 0; i < EE; ++i) hb0 += (i < e) ? cnt[i * CSTRIDE] : 0;
  int mBase = blockIdx.x * 128;
  if (mBase >= cn) return;
  int nBase = blockIdx.y * 64;

  int wave = tid >> 6, lane = tid & 63;
  if (tid < 128) {
    int g = mBase + tid;
    stok[tid] = list[e * TT + (g < cn ? g : cn - 1)];
  }
  __syncthreads();

  const char* gaddr[4];
  int lofs[4];
#pragma unroll
  for (int j = 0; j < 4; ++j) {
    int c = wave * 256 + j * 64 + lane;   // 0..1023
    const char* g;
    if (c < 512) {
      int r = c >> 2, kc = (c & 3) ^ ((r >> 1) & 3);
      g = (const char*)xb + (size_t)stok[r] * (HH * 2) + kc * 16;
    } else if (c < 768) {
      int cc = c - 512, r = cc >> 2, kc = (cc & 3) ^ ((r >> 1) & 3);
      g = (const char*)gwt + ((size_t)e * II + nBase + r) * (HH * 2) + kc * 16;
    } else {
      int cc = c - 768, r = cc >> 2, kc = (cc & 3) ^ ((r >> 1) & 3);
      g = (const char*)uwt + ((size_t)e * II + nBase + r) * (HH * 2) + kc * 16;
    }
    gaddr[j] = g;
    lofs[j] = c * 16;
  }

  int q = lane >> 4, m16 = lane & 15;
  int wr = wave & 1, wc = wave >> 1;
  int faddrA[4], faddrBg[2], faddrBu[2];
#pragma unroll
  for (int mi = 0; mi < 4; ++mi) {
    int R = wr * 64 + mi * 16 + m16;
    faddrA[mi] = (R * 4 + (q ^ ((R >> 1) & 3))) * 16;
  }
#pragma unroll
  for (int ni = 0; ni < 2; ++ni) {
    int n = wc * 32 + ni * 16 + m16;
    faddrBg[ni] = (512 + n * 4 + (q ^ ((n >> 1) & 3))) * 16;
    faddrBu[ni] = (768 + n * 4 + (q ^ ((n >> 1) & 3))) * 16;
  }

  f32x4 zero4 = {0.f, 0.f, 0.f, 0.f};
  f32x4 accG[4][2], accU[4][2];
#pragma unroll
  for (int mi = 0; mi < 4; ++mi)
#pragma unroll
    for (int ni = 0; ni < 2; ++ni) { accG[mi][ni] = zero4; accU[mi][ni] = zero4; }

  char* smemc = (char*)smem;
#pragma unroll
  for (int j = 0; j < 4; ++j) {
    gl_lds16(gaddr[j], smemc + lofs[j]);
    gaddr[j] += 64;
  }
  __syncthreads();

  const int NK = HH / 32;   // 32 K-steps
  for (int kt = 0; kt < NK; ++kt) {
    int cur = kt & 1;
    if (kt + 1 < NK) {
#pragma unroll
      for (int j = 0; j < 4; ++j) {
        gl_lds16(gaddr[j], smemc + (cur ^ 1) * 16384 + lofs[j]);
        gaddr[j] += 64;
      }
    }
    const char* sb = smemc + cur * 16384;
    bf16x8 aF[4], bG[2], bU[2];
#pragma unroll
    for (int mi = 0; mi < 4; ++mi) aF[mi] = *(const bf16x8*)(sb + faddrA[mi]);
#pragma unroll
    for (int ni = 0; ni < 2; ++ni) {
      bG[ni] = *(const bf16x8*)(sb + faddrBg[ni]);
      bU[ni] = *(const bf16x8*)(sb + faddrBu[ni]);
    }
#pragma unroll
    for (int mi = 0; mi < 4; ++mi)
#pragma unroll
      for (int ni = 0; ni < 2; ++ni) {
        accG[mi][ni] = __builtin_amdgcn_mfma_f32_16x16x32_bf16(aF[mi], bG[ni], accG[mi][ni], 0, 0, 0);
        accU[mi][ni] = __builtin_amdgcn_mfma_f32_16x16x32_bf16(aF[mi], bU[ni], accU[mi][ni], 0, 0, 0);
      }
    __syncthreads();
  }

  int hb = hb0 + mBase;
  int rowsValid = cn - mBase; if (rowsValid > 128) rowsValid = 128;
#pragma unroll
  for (int mi = 0; mi < 4; ++mi)
#pragma unroll
    for (int ni = 0; ni < 2; ++ni)
#pragma unroll
      for (int r = 0; r < 4; ++r) {
        int row = wr * 64 + mi * 16 + q * 4 + r;
        if (row < rowsValid) {
          float g = accG[mi][ni][r], u = accU[mi][ni][r];
          float h = g / (1.f + __expf(-g)) * u;
          hidden[(size_t)(hb + row) * II + nBase + wc * 32 + ni * 16 + m16] = f2bf(h);
        }
      }
}

// ---------------- GEMM2: hidden @ out_w, K-split x2, BK=64 1-phase, fused combine ----------------
// 128(M) x 128(N); z = e*2 + khalf (K range khalf*1024..+1024, 16 K-steps).
// 1024 blocks -> 4/CU. Epilogue: atomicAdd(out[token], w*acc) from zeroed out
// (4 adds per element: 2 experts x 2 K-halves; fp32 reorder noise ~1e-6 << threshold).
__launch_bounds__(256, 4)
__global__ void gemm2_kernel(const unsigned short* __restrict__ hidden,
                             const unsigned short* __restrict__ owt,
                             float* __restrict__ out,
                             const int* __restrict__ cnt, const int* __restrict__ list,
                             const float* __restrict__ rwt) {
  int e = blockIdx.z >> 1;
  int kh = blockIdx.z & 1;
  int cn = cnt[e * CSTRIDE];
  int hb0 = 0;
  for (int i = 0; i < EE; ++i) hb0 += (i < e) ? cnt[i * CSTRIDE] : 0;
  int mBase = blockIdx.x * 128;
  if (mBase >= cn) return;
  int nBase = blockIdx.y * 128;

  __shared__ __align__(16) unsigned short smem[16384];  // 2048 x 16B chunks (one buffer)
  __shared__ int stok[128];
  __shared__ float swt[128];

  int tid = threadIdx.x, wave = tid >> 6, lane = tid & 63;
  int hb = hb0 + mBase;
  if (tid < 128) {
    int g = mBase + tid;
    int gi = g < cn ? g : cn - 1;
    stok[tid] = list[e * TT + gi];
    swt[tid] = rwt[e * TT + gi];
  }
  __syncthreads();

  const char* gaddr[8];
#pragma unroll
  for (int j = 0; j < 8; ++j) {
    int c = wave * 512 + j * 64 + lane;   // 0..2047
    const char* g;
    if (c < 1024) {
      int r = c >> 3, sl = (c & 7) ^ (r & 7);
      g = (const char*)hidden + (size_t)(hb + r) * (II * 2) + kh * 2048 + sl * 16;
    } else {
      int cc = c - 1024, r = cc >> 3, sl = (cc & 7) ^ (r & 7);
      g = (const char*)owt + ((size_t)e * HH + nBase + r) * (II * 2) + kh * 2048 + sl * 16;
    }
    gaddr[j] = g;
  }

  int q = lane >> 4, m16 = lane & 15;
  int wr = wave & 1, wc = wave >> 1;
  int faddrA[4][2], faddrB[4][2];
#pragma unroll
  for (int mi = 0; mi < 4; ++mi) {
    int R = wr * 64 + mi * 16 + m16;
#pragma unroll
    for (int h = 0; h < 2; ++h)
      faddrA[mi][h] = (R * 8 + ((h * 4 + q) ^ (R & 7))) * 16;
  }
#pragma unroll
  for (int ni = 0; ni < 4; ++ni) {
    int n = wc * 64 + ni * 16 + m16;
#pragma unroll
    for (int h = 0; h < 2; ++h)
      faddrB[ni][h] = (1024 + n * 8 + ((h * 4 + q) ^ (n & 7))) * 16;
  }

  f32x4 zero4 = {0.f, 0.f, 0.f, 0.f};
  f32x4 acc[4][4];
#pragma unroll
  for (int mi = 0; mi < 4; ++mi)
#pragma unroll
    for (int ni = 0; ni < 4; ++ni) acc[mi][ni] = zero4;

  const char* smemc = (const char*)smem;
  const int NK = 1024 / 64;   // 16 K-steps per half
  for (int kt = 0; kt < NK; ++kt) {
    __syncthreads();
#pragma unroll
    for (int j = 0; j < 8; ++j) {
      gl_lds16(gaddr[j], (char*)smem + (size_t)(wave * 512 + j * 64) * 16);
      gaddr[j] += 128;
    }
    __syncthreads();
#pragma unroll
    for (int h = 0; h < 2; ++h) {
      bf16x8 aF[4], bF[4];
#pragma unroll
      for (int mi = 0; mi < 4; ++mi) aF[mi] = *(const bf16x8*)(smemc + faddrA[mi][h]);
#pragma unroll
      for (int ni = 0; ni < 4; ++ni) bF[ni] = *(const bf16x8*)(smemc + faddrB[ni][h]);
#pragma unroll
      for (int mi = 0; mi < 4; ++mi)
#pragma unroll
        for (int ni = 0; ni < 4; ++ni)
          acc[mi][ni] = __builtin_amdgcn_mfma_f32_16x16x32_bf16(aF[mi], bF[ni], acc[mi][ni], 0, 0, 0);
    }
  }

  int rowsValid = cn - mBase; if (rowsValid > 128) rowsValid = 128;
#pragma unroll
  for (int mi = 0; mi < 4; ++mi)
#pragma unroll
    for (int r = 0; r < 4; ++r) {
      int row = wr * 64 + mi * 16 + q * 4 + r;
      if (row < rowsValid) {
        int t = stok[row];
        float w = swt[row];
        float* orow = out + (size_t)t * HH + nBase + wc * 64 + m16;
#pragma unroll
        for (int ni = 0; ni < 4; ++ni)
          atomicAdd(orow + ni * 16, w * acc[mi][ni][r]);
      }
    }
}

extern "C" void kernel_launch(void* const* d_in, const int* in_sizes, int n_in,
                              void* d_out, int out_size, void* d_ws, size_t ws_size,
                              hipStream_t stream) {
  (void)in_sizes; (void)n_in; (void)out_size; (void)ws_size;
  const float* x  = (const float*)d_in[0];
  const float* rw = (const float*)d_in[1];
  const float* gw = (const float*)d_in[2];
  const float* uw = (const float*)d_in[3];
  const float* ow = (const float*)d_in[4];
  float* out = (float*)d_out;                 // [T*H]
  float* logits = out + (size_t)TT * HH;      // [T*E]

  char* ws = (char*)d_ws;
  size_t o = 0;
  auto alloc = [&](size_t bytes) {
    char* p = ws + o;
    o += (bytes + 255) & ~(size_t)255;
    return p;
  };
  unsigned short* xb  = (unsigned short*)alloc((size_t)TT * HH * 2);
  unsigned short* gwt = (unsigned short*)alloc((size_t)EE * II * HH * 2);
  unsigned short* uwt = (unsigned short*)alloc((size_t)EE * II * HH * 2);
  unsigned short* owt = (unsigned short*)alloc((size_t)EE * HH * II * 2);
  unsigned short* hidden = (unsigned short*)alloc((size_t)(2 * TT + 128) * II * 2);
  int*    cnt   = (int*)alloc(EE * CSTRIDE * 4);
  int*    list  = (int*)alloc((size_t)EE * TT * 4);
  float*  rwt   = (float*)alloc((size_t)EE * TT * 4);
  int*    gcnt  = (int*)alloc((size_t)NRB * EE * 4);
  int2*   ttop  = (int2*)alloc((size_t)TT * 8);

  front_kernel<<<NRB + NTRB + NZB, 256, 0, stream>>>(x, rw, gw, uw, logits, xb, gwt, uwt,
                                                     gcnt, ttop, out);
  scatter_kernel<<<TT / 256, 256, 0, stream>>>(gcnt, ttop, cnt, list, rwt);
  gemm1_kernel<<<dim3(32, 40, EE), 256, 0, stream>>>(xb, gwt, uwt, ow, owt, hidden, cnt, list);
  gemm2_kernel<<<dim3(TT / 128, HH / 128, EE * 2), 256, 0, stream>>>(hidden, owt, out, cnt, list, rwt);
}

// Round 9
// 398.335 us; speedup vs baseline: 1.8602x; 1.8602x over previous
//
#include <hip/hip_runtime.h>
#include <hip/hip_bf16.h>
#include <stdint.h>

#define TT 4096   // tokens = B*S
#define HH 1024   // hidden
#define II 2048   // intermediate
#define EE 8      // experts
#define RB 16     // router tokens per block
#define NRB (TT / RB)          // 256 router blocks
#define CSTRIDE 32             // cnt padding: one counter per 128-B line
#define NTRB (2 * 2048)        // gate/up transpose blocks in front
#define NZB 256                // zero blocks

typedef short bf16x8 __attribute__((ext_vector_type(8)));
typedef float f32x4 __attribute__((ext_vector_type(4)));

__device__ __forceinline__ unsigned short f2bf(float f) {
  unsigned u = __float_as_uint(f);
  u += 0x7FFF + ((u >> 16) & 1);   // RNE
  return (unsigned short)(u >> 16);
}

__device__ __forceinline__ void gl_lds16(const void* g, void* l) {
  auto gp = reinterpret_cast<const __attribute__((address_space(1))) unsigned int*>(
      reinterpret_cast<uintptr_t>(g));
  auto lp = reinterpret_cast<__attribute__((address_space(3))) unsigned int*>(
      reinterpret_cast<uintptr_t>(l));
  __builtin_amdgcn_global_load_lds(gp, lp, 16, 0, 0);
}

// ------- 64(M) x 128(N) transpose tile: in[M][N] fp32 -> out[N][M] bf16 -------
__device__ __forceinline__ void transpose_tile_wide(const float* __restrict__ in,
                                                    unsigned short* __restrict__ out,
                                                    int M, int N, int mB, int nB,
                                                    unsigned int* tl, int tid) {
  union F4 { float4 v; float f[4]; };
  int n4 = tid & 31;          // col quad 0..31
  int mph = tid >> 5;         // 0..7
  F4 a[4], bq[4];
  const float* base = in + (size_t)mB * N + nB + n4 * 4;
#pragma unroll
  for (int it = 0; it < 4; ++it) {
    const float* p = base + (size_t)(2 * (mph + it * 8)) * N;
    a[it].v = *(const float4*)p;
    bq[it].v = *(const float4*)(p + N);
  }
#pragma unroll
  for (int it = 0; it < 4; ++it) {
    int mp = mph + it * 8;    // 0..31
#pragma unroll
    for (int i = 0; i < 4; ++i) {
      int n = n4 * 4 + i;
      unsigned v = (unsigned)f2bf(a[it].f[i]) | ((unsigned)f2bf(bq[it].f[i]) << 16);
      tl[n * 32 + ((mp + (n >> 2) + (n & 3)) & 31)] = v;
    }
  }
  __syncthreads();
  int md = tid & 7;           // dword group (x4)
  int nr = tid >> 3;          // 0..31
#pragma unroll
  for (int it = 0; it < 4; ++it) {
    int n = nr + it * 32;     // 0..127
    int rot = (n >> 2) + (n & 3);
    unsigned vv[4];
#pragma unroll
    for (int k = 0; k < 4; ++k)
      vv[k] = tl[n * 32 + ((md * 4 + k + rot) & 31)];
    *(uint4*)(out + (size_t)(nB + n) * M + mB + md * 8) = make_uint4(vv[0], vv[1], vv[2], vv[3]);
  }
}

// ------- front: router + gate/up transposes + out-buffer zeroing -------
__global__ __launch_bounds__(256, 4)
void front_kernel(const float* __restrict__ x, const float* __restrict__ rw,
                  const float* __restrict__ gw, const float* __restrict__ uw,
                  float* __restrict__ logits_out, unsigned short* __restrict__ xb,
                  unsigned short* __restrict__ gwt, unsigned short* __restrict__ uwt,
                  int* __restrict__ gcnt, int2* __restrict__ ttop,
                  float* __restrict__ outz) {
  __shared__ unsigned int tl[4096];   // 16 KB
  int b = blockIdx.x;
  int tid = threadIdx.x;

  if (b >= NRB + NTRB) {
    int zb = b - NRB - NTRB;              // 0..255
    float4* o = (float4*)outz + (size_t)zb * 4096 + tid;
    float4 z = make_float4(0.f, 0.f, 0.f, 0.f);
#pragma unroll
    for (int k = 0; k < 16; ++k) o[k * 256] = z;
    return;
  }

  if (b >= NRB) {
    int idx = b - NRB;           // 0..4095
    int which = idx >> 11;       // 0 gate, 1 up
    int r = idx & 2047;
    int e = r >> 8;              // 256 tiles per expert per matrix
    int tile = r & 255;
    int bx = tile & 15, by = tile >> 4;
    const float* in = (which ? uw : gw) + (size_t)e * HH * II;
    unsigned short* o = (which ? uwt : gwt) + (size_t)e * HH * II;
    transpose_tile_wide(in, o, HH, II, by * 64, bx * 128, tl, tid);
    return;
  }

  __shared__ int bcnt[EE];
  int wave = tid >> 6, lane = tid & 63;
  if (tid < EE) bcnt[tid] = 0;
  __syncthreads();
  int t0 = b * RB;

  for (int sub = 0; sub < RB / 4; ++sub) {
    int li = sub * 4 + wave;
    int t = t0 + li;
    float acc[EE];
#pragma unroll
    for (int e = 0; e < EE; ++e) acc[e] = 0.f;
#pragma unroll
    for (int j = 0; j < 4; ++j) {
      int h = j * 256 + lane * 4;
      union F4 { float4 v; float f[4]; } xv;
      xv.v = *(const float4*)(x + (size_t)t * HH + h);
      union { unsigned short s[4]; uint2 v; } pk;
#pragma unroll
      for (int i = 0; i < 4; ++i) pk.s[i] = f2bf(xv.f[i]);
      *(uint2*)(xb + (size_t)t * HH + h) = pk.v;
#pragma unroll
      for (int i = 0; i < 4; ++i) {
        const float4* r4 = (const float4*)(rw + (h + i) * EE);
        float4 r0 = r4[0], r1 = r4[1];
        float xs = xv.f[i];
        acc[0] += xs * r0.x; acc[1] += xs * r0.y; acc[2] += xs * r0.z; acc[3] += xs * r0.w;
        acc[4] += xs * r1.x; acc[5] += xs * r1.y; acc[6] += xs * r1.z; acc[7] += xs * r1.w;
      }
    }
#pragma unroll
    for (int e = 0; e < EE; ++e)
#pragma unroll
      for (int off = 32; off; off >>= 1) acc[e] += __shfl_down(acc[e], off);
    if (lane == 0) {
      float4* lo = (float4*)(logits_out + (size_t)t * EE);
      lo[0] = make_float4(acc[0], acc[1], acc[2], acc[3]);
      lo[1] = make_float4(acc[4], acc[5], acc[6], acc[7]);
      int e0 = 0; float b0 = acc[0];
#pragma unroll
      for (int e = 1; e < EE; ++e) if (acc[e] > b0) { b0 = acc[e]; e0 = e; }
      int e1 = -1; float b1 = -3.4e38f;
#pragma unroll
      for (int e = 0; e < EE; ++e) if (e != e0 && acc[e] > b1) { b1 = acc[e]; e1 = e; }
      float w0 = 1.f / (1.f + __expf(b1 - b0));
      int lp0 = atomicAdd(&bcnt[e0], 1);   // LDS atomic, intra-block only
      int lp1 = atomicAdd(&bcnt[e1], 1);
      ttop[t] = make_int2(e0 | (e1 << 3) | (lp0 << 6) | (lp1 << 11), __float_as_int(w0));
    }
  }
  __syncthreads();
  if (tid < EE) gcnt[b * EE + tid] = bcnt[tid];
}

// ------- scatter: deterministic token placement; emits per-(e,slot) token + weight -------
__global__ void scatter_kernel(const int* __restrict__ gcnt, const int2* __restrict__ ttop,
                               int* __restrict__ cnt, int* __restrict__ list,
                               float* __restrict__ rwt) {
  __shared__ int raw[NRB * EE];
  __shared__ int base[NRB][EE];
  int tid = threadIdx.x;
  for (int i = tid; i < NRB * EE; i += 256) raw[i] = gcnt[i];
  __syncthreads();
  if (tid < EE) {
    int s = 0;
    for (int b = 0; b < NRB; ++b) { base[b][tid] = s; s += raw[b * EE + tid]; }
    if (blockIdx.x == 0) cnt[tid * CSTRIDE] = s;
  }
  __syncthreads();
  int t = blockIdx.x * 256 + tid;
  int2 ti = ttop[t];
  int v = ti.x;
  float w0 = __int_as_float(ti.y);
  int e0 = v & 7, e1 = (v >> 3) & 7, lp0 = (v >> 6) & 31, lp1 = (v >> 11) & 31;
  int b = t >> 4;
  int p0 = base[b][e0] + lp0;
  int p1 = base[b][e1] + lp1;
  list[e0 * TT + p0] = t;
  list[e1 * TT + p1] = t;
  rwt[e0 * TT + p0] = w0;
  rwt[e1 * TT + p1] = 1.f - w0;
}

// ---------------- GEMM1: 128(M) x 64(N) x2 tensors, BK=64 1-phase (measured-best body) ----------------
// grid dim3(32, 40, EE): y=m-tile (y>=32: embedded out_w transpose), x=n-tile FASTEST
// (consecutive blocks share A tokens in L2; B re-reads absorbed by L3 — round-8 lesson).
__launch_bounds__(256, 3)
__global__ void gemm1_kernel(const unsigned short* __restrict__ xb,
                             const unsigned short* __restrict__ gwt,
                             const unsigned short* __restrict__ uwt,
                             const float* __restrict__ ow, unsigned short* __restrict__ owt,
                             unsigned short* __restrict__ hidden,
                             const int* __restrict__ cnt, const int* __restrict__ list) {
  __shared__ __align__(16) unsigned short smem[16384];  // 2048 x 16B chunks (32 KB)
  __shared__ int stok[128];
  int tid = threadIdx.x;
  int e = blockIdx.z;

  if (blockIdx.y >= 32) {
    // out_w transpose: ow [II][HH] -> owt [HH][II] for expert e (256 tiles of 64x128)
    int tile = (blockIdx.y - 32) * 32 + blockIdx.x;  // 0..255
    int bx = tile & 7, by = tile >> 3;               // N/128=8, M/64=32
    transpose_tile_wide(ow + (size_t)e * II * HH, owt + (size_t)e * II * HH,
                        II, HH, by * 64, bx * 128, (unsigned int*)smem, tid);
    return;
  }

  int cn = cnt[e * CSTRIDE];
  int hb0 = 0;
  for (int i = 0; i < EE; ++i) hb0 += (i < e) ? cnt[i * CSTRIDE] : 0;
  int mBase = blockIdx.y * 128;
  if (mBase >= cn) return;
  int nBase = blockIdx.x * 64;

  int wave = tid >> 6, lane = tid & 63;
  if (tid < 128) {
    int g = mBase + tid;
    stok[tid] = list[e * TT + (g < cn ? g : cn - 1)];
  }
  __syncthreads();

  const char* gaddr[8];
#pragma unroll
  for (int j = 0; j < 8; ++j) {
    int c = wave * 512 + j * 64 + lane;   // 0..2047
    const char* g;
    if (c < 1024) {
      int r = c >> 3, sl = (c & 7) ^ (r & 7);
      g = (const char*)xb + (size_t)stok[r] * (HH * 2) + sl * 16;
    } else if (c < 1536) {
      int cc = c - 1024, r = cc >> 3, sl = (cc & 7) ^ (r & 7);
      g = (const char*)gwt + ((size_t)e * II + nBase + r) * (HH * 2) + sl * 16;
    } else {
      int cc = c - 1536, r = cc >> 3, sl = (cc & 7) ^ (r & 7);
      g = (const char*)uwt + ((size_t)e * II + nBase + r) * (HH * 2) + sl * 16;
    }
    gaddr[j] = g;
  }

  int q = lane >> 4, m16 = lane & 15;
  int wr = wave & 1, wc = wave >> 1;
  int faddrA[4][2], faddrBg[2][2], faddrBu[2][2];
#pragma unroll
  for (int mi = 0; mi < 4; ++mi) {
    int R = wr * 64 + mi * 16 + m16;
#pragma unroll
    for (int h = 0; h < 2; ++h)
      faddrA[mi][h] = (R * 8 + ((h * 4 + q) ^ (R & 7))) * 16;
  }
#pragma unroll
  for (int ni = 0; ni < 2; ++ni) {
    int n = wc * 32 + ni * 16 + m16;
#pragma unroll
    for (int h = 0; h < 2; ++h) {
      faddrBg[ni][h] = (1024 + n * 8 + ((h * 4 + q) ^ (n & 7))) * 16;
      faddrBu[ni][h] = (1536 + n * 8 + ((h * 4 + q) ^ (n & 7))) * 16;
    }
  }

  f32x4 zero4 = {0.f, 0.f, 0.f, 0.f};
  f32x4 accG[4][2], accU[4][2];
#pragma unroll
  for (int mi = 0; mi < 4; ++mi)
#pragma unroll
    for (int ni = 0; ni < 2; ++ni) { accG[mi][ni] = zero4; accU[mi][ni] = zero4; }

  const char* smemc = (const char*)smem;
  for (int kt = 0; kt < HH / 64; ++kt) {
    __syncthreads();
#pragma unroll
    for (int j = 0; j < 8; ++j) {
      gl_lds16(gaddr[j], (char*)smem + (size_t)(wave * 512 + j * 64) * 16);
      gaddr[j] += 128;
    }
    __syncthreads();
#pragma unroll
    for (int h = 0; h < 2; ++h) {
      bf16x8 aF[4], bG[2], bU[2];
#pragma unroll
      for (int mi = 0; mi < 4; ++mi) aF[mi] = *(const bf16x8*)(smemc + faddrA[mi][h]);
#pragma unroll
      for (int ni = 0; ni < 2; ++ni) {
        bG[ni] = *(const bf16x8*)(smemc + faddrBg[ni][h]);
        bU[ni] = *(const bf16x8*)(smemc + faddrBu[ni][h]);
      }
#pragma unroll
      for (int mi = 0; mi < 4; ++mi)
#pragma unroll
        for (int ni = 0; ni < 2; ++ni) {
          accG[mi][ni] = __builtin_amdgcn_mfma_f32_16x16x32_bf16(aF[mi], bG[ni], accG[mi][ni], 0, 0, 0);
          accU[mi][ni] = __builtin_amdgcn_mfma_f32_16x16x32_bf16(aF[mi], bU[ni], accU[mi][ni], 0, 0, 0);
        }
    }
  }

  int hb = hb0 + mBase;
  int rowsValid = cn - mBase; if (rowsValid > 128) rowsValid = 128;
#pragma unroll
  for (int mi = 0; mi < 4; ++mi)
#pragma unroll
    for (int ni = 0; ni < 2; ++ni)
#pragma unroll
      for (int r = 0; r < 4; ++r) {
        int row = wr * 64 + mi * 16 + q * 4 + r;
        if (row < rowsValid) {
          float g = accG[mi][ni][r], u = accU[mi][ni][r];
          float h = g / (1.f + __expf(-g)) * u;
          hidden[(size_t)(hb + row) * II + nBase + wc * 32 + ni * 16 + m16] = f2bf(h);
        }
      }
}

// ---------------- GEMM2: hidden @ out_w, 128(M) x 128(N), BK=64 1-phase, fused combine ----------------
// grid dim3(8, 32, EE): x=n-tile fastest, y=m-tile. Epilogue: atomicAdd(out[token], w*acc)
// from zeroed out (exactly 2 adds per element; 2-term fp32 add is order-independent).
__launch_bounds__(256, 3)
__global__ void gemm2_kernel(const unsigned short* __restrict__ hidden,
                             const unsigned short* __restrict__ owt,
                             float* __restrict__ out,
                             const int* __restrict__ cnt, const int* __restrict__ list,
                             const float* __restrict__ rwt) {
  int e = blockIdx.z;
  int cn = cnt[e * CSTRIDE];
  int hb0 = 0;
  for (int i = 0; i < EE; ++i) hb0 += (i < e) ? cnt[i * CSTRIDE] : 0;
  int mBase = blockIdx.y * 128;
  if (mBase >= cn) return;
  int nBase = blockIdx.x * 128;

  __shared__ __align__(16) unsigned short smem[16384];  // 2048 x 16B chunks (32 KB)
  __shared__ int stok[128];
  __shared__ float swt[128];

  int tid = threadIdx.x, wave = tid >> 6, lane = tid & 63;
  int hb = hb0 + mBase;
  if (tid < 128) {
    int g = mBase + tid;
    int gi = g < cn ? g : cn - 1;
    stok[tid] = list[e * TT + gi];
    swt[tid] = rwt[e * TT + gi];
  }

  const char* gaddr[8];
#pragma unroll
  for (int j = 0; j < 8; ++j) {
    int c = wave * 512 + j * 64 + lane;   // 0..2047
    const char* g;
    if (c < 1024) {
      int r = c >> 3, sl = (c & 7) ^ (r & 7);
      g = (const char*)hidden + (size_t)(hb + r) * (II * 2) + sl * 16;
    } else {
      int cc = c - 1024, r = cc >> 3, sl = (cc & 7) ^ (r & 7);
      g = (const char*)owt + ((size_t)e * HH + nBase + r) * (II * 2) + sl * 16;
    }
    gaddr[j] = g;
  }

  int q = lane >> 4, m16 = lane & 15;
  int wr = wave & 1, wc = wave >> 1;
  int faddrA[4][2], faddrB[4][2];
#pragma unroll
  for (int mi = 0; mi < 4; ++mi) {
    int R = wr * 64 + mi * 16 + m16;
#pragma unroll
    for (int h = 0; h < 2; ++h)
      faddrA[mi][h] = (R * 8 + ((h * 4 + q) ^ (R & 7))) * 16;
  }
#pragma unroll
  for (int ni = 0; ni < 4; ++ni) {
    int n = wc * 64 + ni * 16 + m16;
#pragma unroll
    for (int h = 0; h < 2; ++h)
      faddrB[ni][h] = (1024 + n * 8 + ((h * 4 + q) ^ (n & 7))) * 16;
  }

  f32x4 zero4 = {0.f, 0.f, 0.f, 0.f};
  f32x4 acc[4][4];
#pragma unroll
  for (int mi = 0; mi < 4; ++mi)
#pragma unroll
    for (int ni = 0; ni < 4; ++ni) acc[mi][ni] = zero4;

  const char* smemc = (const char*)smem;
  for (int kt = 0; kt < II / 64; ++kt) {
    __syncthreads();
#pragma unroll
    for (int j = 0; j < 8; ++j) {
      gl_lds16(gaddr[j], (char*)smem + (size_t)(wave * 512 + j * 64) * 16);
      gaddr[j] += 128;
    }
    __syncthreads();
#pragma unroll
    for (int h = 0; h < 2; ++h) {
      bf16x8 aF[4], bF[4];
#pragma unroll
      for (int mi = 0; mi < 4; ++mi) aF[mi] = *(const bf16x8*)(smemc + faddrA[mi][h]);
#pragma unroll
      for (int ni = 0; ni < 4; ++ni) bF[ni] = *(const bf16x8*)(smemc + faddrB[ni][h]);
#pragma unroll
      for (int mi = 0; mi < 4; ++mi)
#pragma unroll
        for (int ni = 0; ni < 4; ++ni)
          acc[mi][ni] = __builtin_amdgcn_mfma_f32_16x16x32_bf16(aF[mi], bF[ni], acc[mi][ni], 0, 0, 0);
    }
  }

  int rowsValid = cn - mBase; if (rowsValid > 128) rowsValid = 128;
#pragma unroll
  for (int mi = 0; mi < 4; ++mi)
#pragma unroll
    for (int r = 0; r < 4; ++r) {
      int row = wr * 64 + mi * 16 + q * 4 + r;
      if (row < rowsValid) {
        int t = stok[row];
        float w = swt[row];
        float* orow = out + (size_t)t * HH + nBase + wc * 64 + m16;
#pragma unroll
        for (int ni = 0; ni < 4; ++ni)
          atomicAdd(orow + ni * 16, w * acc[mi][ni][r]);
      }
    }
}

extern "C" void kernel_launch(void* const* d_in, const int* in_sizes, int n_in,
                              void* d_out, int out_size, void* d_ws, size_t ws_size,
                              hipStream_t stream) {
  (void)in_sizes; (void)n_in; (void)out_size; (void)ws_size;
  const float* x  = (const float*)d_in[0];
  const float* rw = (const float*)d_in[1];
  const float* gw = (const float*)d_in[2];
  const float* uw = (const float*)d_in[3];
  const float* ow = (const float*)d_in[4];
  float* out = (float*)d_out;                 // [T*H]
  float* logits = out + (size_t)TT * HH;      // [T*E]

  char* ws = (char*)d_ws;
  size_t o = 0;
  auto alloc = [&](size_t bytes) {
    char* p = ws + o;
    o += (bytes + 255) & ~(size_t)255;
    return p;
  };
  unsigned short* xb  = (unsigned short*)alloc((size_t)TT * HH * 2);
  unsigned short* gwt = (unsigned short*)alloc((size_t)EE * II * HH * 2);
  unsigned short* uwt = (unsigned short*)alloc((size_t)EE * II * HH * 2);
  unsigned short* owt = (unsigned short*)alloc((size_t)EE * HH * II * 2);
  unsigned short* hidden = (unsigned short*)alloc((size_t)(2 * TT + 128) * II * 2);
  int*    cnt   = (int*)alloc(EE * CSTRIDE * 4);
  int*    list  = (int*)alloc((size_t)EE * TT * 4);
  float*  rwt   = (float*)alloc((size_t)EE * TT * 4);
  int*    gcnt  = (int*)alloc((size_t)NRB * EE * 4);
  int2*   ttop  = (int2*)alloc((size_t)TT * 8);

  front_kernel<<<NRB + NTRB + NZB, 256, 0, stream>>>(x, rw, gw, uw, logits, xb, gwt, uwt,
                                                     gcnt, ttop, out);
  scatter_kernel<<<TT / 256, 256, 0, stream>>>(gcnt, ttop, cnt, list, rwt);
  gemm1_kernel<<<dim3(32, 40, EE), 256, 0, stream>>>(xb, gwt, uwt, ow, owt, hidden, cnt, list);
  gemm2_kernel<<<dim3(HH / 128, TT / 128, EE), 256, 0, stream>>>(hidden, owt, out, cnt, list, rwt);
}